// Round 8
// baseline (96.407 us; speedup 1.0000x reference)
//
#include <hip/hip_runtime.h>
#include <math.h>

#define B  16
#define LQ 256
#define LC 256
#define D  64
#define QT 4
#define TS   2.88539008177793f    // 2*log2(e)
#define L2E  1.44269504088896f    // log2(e)
#define PAD  72                   // LDS row stride (floats) for w_t [k][64]
#define INPAD 36                  // LDS row stride for in_t [k][32]
#define TPAD 33                   // LDS row stride for transpose tile [e][32]
#define CP4  264                  // esct pitch in float4 units (4224B, non-pow2)

// ---------------------------------------------------------------------------
// fused_kernel: ONE plain launch, 1024 blocks x 256 threads, exactly 4
// blocks/CU co-resident (LDS 36.1KB caps at 4/CU; launch_bounds(256,4) caps
// VGPR at 128; grid == 4 x 256 CUs -> guide-sanctioned co-residency).
// Phase 1 (blocks 0..511): R2/R4-proven proj GEMMs -> esq/esct/oq/wb.
// Hand-rolled producer barrier (R7's hipLaunchCooperativeKernel never ran --
// not graph-capturable): producers do agent-scope RELEASE atomicAdd on a
// workspace flag; all blocks spin on agent-scope ACQUIRE load until 512.
// Release/acquire at agent scope = correct cross-XCD L2 ordering; the %8
// XCD pinning remains a locality heuristic only.
// Phase 2 (all blocks): the R6 attn verbatim, LDS overlaid.
// ---------------------------------------------------------------------------
__global__ __launch_bounds__(256, 4) void fused_kernel(
    const float* __restrict__ query, const float* __restrict__ bank,
    const unsigned char* __restrict__ mask,
    const float* __restrict__ Wq, const float* __restrict__ Wc,
    const float* __restrict__ bc, const float* __restrict__ Ws,
    const float* __restrict__ Woq, const float* __restrict__ Woc,
    const float* __restrict__ boc,
    float* __restrict__ esq, float* __restrict__ esct,
    float* __restrict__ oq, float* __restrict__ wb,
    unsigned int* __restrict__ flag,
    float* __restrict__ out, float* __restrict__ attn_out)
{
    __shared__ __align__(16) float smem[64*INPAD + 64*PAD + 64*TPAD];
    int t = threadIdx.x;

    // ======================= phase 1: projections ==========================
    if (blockIdx.x < 512) {
        float* in_t = smem;                        // [k][32]
        float* w_t  = smem + 64*INPAD;             // [k][64]
        float* tr   = smem + 64*INPAD + 64*PAD;    // [e][32], tp==1 only

        int tp = blockIdx.x >> 7;
        int rb = blockIdx.x & 127;
        // batch-aligned remap: bb = (rb&7)+8*(rb>>6), j = (rb>>3)&7
        int bb_x = (rb & 7) + ((rb >> 6) << 3);
        int jj   = (rb >> 3) & 7;
        int r0 = bb_x * 256 + jj * 32;

        const float* src = (tp & 1) ? bank : query;      // tp 1,3 -> bank
        const float* W   = (tp == 0) ? Wq : (tp == 1) ? Wc : (tp == 2) ? Woq : Woc;

        #pragma unroll
        for (int it = 0; it < 2; ++it) {
            int g = it * 256 + t;
            int kc4 = g & 15, row = g >> 4;              // row 0..31
            float4 v = *reinterpret_cast<const float4*>(src + (r0 + row) * D + kc4 * 4);
            in_t[(kc4*4+0)*INPAD + row] = v.x; in_t[(kc4*4+1)*INPAD + row] = v.y;
            in_t[(kc4*4+2)*INPAD + row] = v.z; in_t[(kc4*4+3)*INPAD + row] = v.w;
        }
        #pragma unroll
        for (int it = 0; it < 4; ++it) {
            int g = it * 256 + t;
            int kc = (g >> 8) * 4 + (g & 3);
            int row = (g >> 2) & 63;
            float4 w = *reinterpret_cast<const float4*>(W + row * D + kc * 4);
            w_t[(kc*4+0)*PAD + row] = w.x; w_t[(kc*4+1)*PAD + row] = w.y;
            w_t[(kc*4+2)*PAD + row] = w.z; w_t[(kc*4+3)*PAD + row] = w.w;
        }
        __syncthreads();

        int cg_ = t & 15, rg = t >> 4;
        float acc[2][4];
        #pragma unroll
        for (int i = 0; i < 2; ++i)
            #pragma unroll
            for (int j = 0; j < 4; ++j) acc[i][j] = 0.f;

        #pragma unroll 8
        for (int k = 0; k < 64; ++k) {
            float2 a2 = *reinterpret_cast<const float2*>(&in_t[k * INPAD + rg * 2]);
            float4 w4 = *reinterpret_cast<const float4*>(&w_t [k * PAD + cg_ * 4]);
            acc[0][0]=fmaf(a2.x,w4.x,acc[0][0]); acc[0][1]=fmaf(a2.x,w4.y,acc[0][1]);
            acc[0][2]=fmaf(a2.x,w4.z,acc[0][2]); acc[0][3]=fmaf(a2.x,w4.w,acc[0][3]);
            acc[1][0]=fmaf(a2.y,w4.x,acc[1][0]); acc[1][1]=fmaf(a2.y,w4.y,acc[1][1]);
            acc[1][2]=fmaf(a2.y,w4.z,acc[1][2]); acc[1][3]=fmaf(a2.y,w4.w,acc[1][3]);
        }

        float4 b4 = {0.f, 0.f, 0.f, 0.f};
        if (tp == 1) b4 = *reinterpret_cast<const float4*>(bc  + cg_ * 4);
        if (tp == 3) b4 = *reinterpret_cast<const float4*>(boc + cg_ * 4);

        if (tp == 1) {
            #pragma unroll
            for (int i = 0; i < 2; ++i) {
                tr[(cg_*4+0)*TPAD + rg*2+i] = exp2f(TS * (acc[i][0] + b4.x));
                tr[(cg_*4+1)*TPAD + rg*2+i] = exp2f(TS * (acc[i][1] + b4.y));
                tr[(cg_*4+2)*TPAD + rg*2+i] = exp2f(TS * (acc[i][2] + b4.z));
                tr[(cg_*4+3)*TPAD + rg*2+i] = exp2f(TS * (acc[i][3] + b4.w));
            }
            __syncthreads();
            int bb = r0 >> 8;            // batch index
            int cbase = r0 & 255;        // c offset within batch
            #pragma unroll
            for (int it = 0; it < 2; ++it) {
                int g = it * 256 + t;
                int d4 = g >> 5, cl = g & 31;
                float4 o;
                o.x = tr[(4*d4+0)*TPAD + cl];
                o.y = tr[(4*d4+1)*TPAD + cl];
                o.z = tr[(4*d4+2)*TPAD + cl];
                o.w = tr[(4*d4+3)*TPAD + cl];
                *reinterpret_cast<float4*>(esct + ((bb*16 + d4)*CP4 + cbase + cl)*4) = o;
            }
        } else {
            float* dst = (tp == 0) ? esq : (tp == 2) ? oq : wb;
            #pragma unroll
            for (int i = 0; i < 2; ++i) {
                float4 o;
                o.x = acc[i][0] + b4.x; o.y = acc[i][1] + b4.y;
                o.z = acc[i][2] + b4.z; o.w = acc[i][3] + b4.w;
                if (tp == 0) {
                    o.x = exp2f(TS * o.x); o.y = exp2f(TS * o.y);
                    o.z = exp2f(TS * o.z); o.w = exp2f(TS * o.w);
                }
                *reinterpret_cast<float4*>(dst + (r0 + rg*2 + i) * D + cg_ * 4) = o;
            }
        }
    }

    // block-wide: all phase-1 global stores drained (per-wave vmcnt before
    // barrier) and all phase-1 LDS reads complete (overlay safety).
    __syncthreads();

    // producer signal: agent-scope RELEASE (writes back XCD L2 -> LLC)
    if (blockIdx.x < 512 && t == 0)
        __hip_atomic_fetch_add(flag, 1u, __ATOMIC_RELEASE, __HIP_MEMORY_SCOPE_AGENT);

    // ---- attn decode + mask prefetch (input-only, overlaps the spin) ----
    int c = t;
    int p = blockIdx.x;
    int b = (p & 7) + ((p >> 9) << 3);
    int qb = (p >> 3) & 63;
    int bq0 = b * LQ + qb * QT;
    int lane = t & 63, wv = t >> 6;

    unsigned char mb[QT];
    #pragma unroll
    for (int qi = 0; qi < QT; ++qi) mb[qi] = mask[(bq0 + qi) * LC + c];

    // ---- spin until all 512 producers signaled (agent-scope ACQUIRE) ----
    if (t == 0) {
        while (__hip_atomic_load(flag, __ATOMIC_ACQUIRE, __HIP_MEMORY_SCOPE_AGENT) < 512u)
            __builtin_amdgcn_s_sleep(4);
    }
    __syncthreads();

    // ======================= phase 2: attention ============================
    float* esq_lds = smem;                                       // [QT][D]
    float (*a_lds)[LC] = reinterpret_cast<float(*)[LC]>(smem + QT*D);
    float* part_lds = smem + QT*D + QT*LC;                       // [4*QT*64]
    float* red_s    = smem + QT*D + QT*LC + 4*QT*64;             // [4*QT]

    // stage esq: one coalesced 1KB read (4 rows x 64 = 1 float/thread)
    esq_lds[t] = esq[bq0 * D + t];
    __syncthreads();

    const float4* ep4 = reinterpret_cast<const float4*>(esct) + b*16*CP4 + c;

    float s[QT];
    #pragma unroll
    for (int qi = 0; qi < QT; ++qi) s[qi] = 0.f;

    // score: esq via wave-uniform ds_read_b128 broadcast, Ws via s_load,
    // 4-way-paired rcp body
    #pragma unroll
    for (int kb = 0; kb < 4; ++kb) {
        float4 ec4[4];
        #pragma unroll
        for (int j = 0; j < 4; ++j) ec4[j] = ep4[(kb*4 + j) * CP4];
        #pragma unroll
        for (int j = 0; j < 4; ++j) {
            const int d0 = kb * 16 + j * 4;
            float w0 = Ws[d0+0], w1 = Ws[d0+1];
            float w2 = Ws[d0+2], w3 = Ws[d0+3];
            #pragma unroll
            for (int qi = 0; qi < QT; ++qi) {
                float4 e4 = *reinterpret_cast<const float4*>(&esq_lds[qi*D + d0]);
                float ax = fmaf(ec4[j].x, e4.x, 1.0f);
                float ay = fmaf(ec4[j].y, e4.y, 1.0f);
                float az = fmaf(ec4[j].z, e4.z, 1.0f);
                float aw = fmaf(ec4[j].w, e4.w, 1.0f);
                float pxy = ax * ay, pzw = az * aw;
                float nxy = fmaf(w0, ay, w1 * ax);
                float nzw = fmaf(w2, aw, w3 * az);
                float N   = fmaf(nxy, pzw, nzw * pxy);
                s[qi] = fmaf(N, __builtin_amdgcn_rcpf(pxy * pzw), s[qi]);
            }
        }
    }

    // unnormalized weights: tanh-bounded scores -> no max-subtraction needed
    float a[QT];
    #pragma unroll
    for (int qi = 0; qi < QT; ++qi) {
        a[qi] = mb[qi] ? 0.0f : exp2f(-TS * s[qi]);
    }

    // stage UNNORMALIZED weights for context; SUM reduce shares the barrier
    #pragma unroll
    for (int qi = 0; qi < QT; ++qi) a_lds[qi][c] = a[qi];
    #pragma unroll
    for (int qi = 0; qi < QT; ++qi) {
        float ss = a[qi];
        #pragma unroll
        for (int o = 32; o > 0; o >>= 1) ss += __shfl_xor(ss, o);
        if (lane == 0) red_s[wv * QT + qi] = ss;
    }
    __syncthreads();

    float rs[QT];
    #pragma unroll
    for (int qi = 0; qi < QT; ++qi) {
        float SUM = (red_s[qi] + red_s[QT + qi]) + (red_s[2*QT + qi] + red_s[3*QT + qi]);
        rs[qi] = __builtin_amdgcn_rcpf(SUM);
    }

    // normalized attention output (terminal stores, off critical path)
    #pragma unroll
    for (int qi = 0; qi < QT; ++qi)
        attn_out[(bq0 + qi) * LC + c] = a[qi] * rs[qi];

    // fused context+output-proj on UNNORMALIZED weights; wave g owns
    // c=g*64..+63; a_lds read as wave-uniform ds_read_b128 broadcasts
    {
        int g = wv;
        float acc[QT];
        #pragma unroll
        for (int qi = 0; qi < QT; ++qi) acc[qi] = 0.f;
        const float* wbp = wb + (b * LC + g * 64) * D + lane;
        #pragma unroll
        for (int i0 = 0; i0 < 64; i0 += 4) {
            float4 A0 = *reinterpret_cast<const float4*>(&a_lds[0][g*64 + i0]);
            float4 A1 = *reinterpret_cast<const float4*>(&a_lds[1][g*64 + i0]);
            float4 A2 = *reinterpret_cast<const float4*>(&a_lds[2][g*64 + i0]);
            float4 A3 = *reinterpret_cast<const float4*>(&a_lds[3][g*64 + i0]);
            float w0 = wbp[(i0+0) * D];
            float w1 = wbp[(i0+1) * D];
            float w2 = wbp[(i0+2) * D];
            float w3 = wbp[(i0+3) * D];
            acc[0] = fmaf(A0.x, w0, acc[0]); acc[1] = fmaf(A1.x, w0, acc[1]);
            acc[2] = fmaf(A2.x, w0, acc[2]); acc[3] = fmaf(A3.x, w0, acc[3]);
            acc[0] = fmaf(A0.y, w1, acc[0]); acc[1] = fmaf(A1.y, w1, acc[1]);
            acc[2] = fmaf(A2.y, w1, acc[2]); acc[3] = fmaf(A3.y, w1, acc[3]);
            acc[0] = fmaf(A0.z, w2, acc[0]); acc[1] = fmaf(A1.z, w2, acc[1]);
            acc[2] = fmaf(A2.z, w2, acc[2]); acc[3] = fmaf(A3.z, w2, acc[3]);
            acc[0] = fmaf(A0.w, w3, acc[0]); acc[1] = fmaf(A1.w, w3, acc[1]);
            acc[2] = fmaf(A2.w, w3, acc[2]); acc[3] = fmaf(A3.w, w3, acc[3]);
        }
        #pragma unroll
        for (int qi = 0; qi < QT; ++qi)
            part_lds[(g * QT + qi) * 64 + lane] = acc[qi];
    }
    __syncthreads();

    {
        int qi = t >> 6, e = t & 63;
        float ps = (part_lds[(0 * QT + qi) * 64 + e] + part_lds[(1 * QT + qi) * 64 + e])
                 + (part_lds[(2 * QT + qi) * 64 + e] + part_lds[(3 * QT + qi) * 64 + e]);
        out[bq0 * D + t] = fmaf(ps, rs[qi], oq[bq0 * D + t]);
    }
}

extern "C" void kernel_launch(void* const* d_in, const int* in_sizes, int n_in,
                              void* d_out, int out_size, void* d_ws, size_t ws_size,
                              hipStream_t stream) {
    const float* query = (const float*)d_in[0];
    const float* bank  = (const float*)d_in[1];
    const unsigned char* mask = (const unsigned char*)d_in[2];
    const float* Wq  = (const float*)d_in[3];
    const float* Wc  = (const float*)d_in[4];
    const float* bc  = (const float*)d_in[5];
    const float* Ws  = (const float*)d_in[6];
    // d_in[7] = bs: row-constant, cancels in softmax
    const float* Woq = (const float*)d_in[8];
    const float* Woc = (const float*)d_in[9];
    const float* boc = (const float*)d_in[10];

    float* out  = (float*)d_out;             // [B,LQ,D]
    float* attn = out + B * LQ * D;          // [B,LQ,LC]

    float* esq  = (float*)d_ws;              // [B*LQ, D]
    float* esct = esq + B * LQ * D;          // [B][16 d4][CP4] float4-interleaved
    float* oq   = esct + B * 16 * CP4 * 4;   // [B*LQ, D]
    float* wb   = oq + B * LQ * D;           // [B*LC, D]
    unsigned int* flag = (unsigned int*)(wb + B * LC * D);

    hipMemsetAsync(flag, 0, sizeof(unsigned int), stream);
    fused_kernel<<<B * LQ / QT, 256, 0, stream>>>(
        query, bank, mask, Wq, Wc, bc, Ws, Woq, Woc, boc,
        esq, esct, oq, wb, flag, out, attn);
}

// Round 9
// 80.833 us; speedup vs baseline: 1.1927x; 1.1927x over previous
//
#include <hip/hip_runtime.h>
#include <math.h>

#define B  16
#define LQ 256
#define LC 256
#define D  64
#define QT 4
#define TS   2.88539008177793f    // 2*log2(e)
#define L2E  1.44269504088896f    // log2(e)
#define PAD  72                   // LDS row stride (floats) for w_t [k][64]
#define INPAD 36                  // LDS row stride for in_t [k][32]
#define TPAD 33                   // LDS row stride for transpose tile [e][32]
#define CP4  264                  // esct pitch in float4 units (4224B, non-pow2)

// ---------------------------------------------------------------------------
// fused_kernel: ONE plain launch, 1024 blocks x 256 threads, exactly 4
// blocks/CU co-resident (36.1KB LDS -> 4/CU; VGPR 52). R8 proved fusion
// correctness and measured VALUBusy*dur ~= 10.4us of real work inside a
// 96us wall -> ~85us was barrier mechanics.
// R9 change (single, isolated): the consumer spin polls with RELAXED
// agent-scope loads (R8's ACQUIRE poll emitted an L2-invalidate PER POLL
// ITERATION from 1024 blocks -- the invalidate storm that nuked the XCD L2s
// while producers worked). One ACQUIRE load after the spin exits provides
// the one-time invalidate that publishes the producers' released stores.
// Producer release (one RELEASE fetch_add per block, L2 writeback) unchanged.
// ---------------------------------------------------------------------------
__global__ __launch_bounds__(256, 4) void fused_kernel(
    const float* __restrict__ query, const float* __restrict__ bank,
    const unsigned char* __restrict__ mask,
    const float* __restrict__ Wq, const float* __restrict__ Wc,
    const float* __restrict__ bc, const float* __restrict__ Ws,
    const float* __restrict__ Woq, const float* __restrict__ Woc,
    const float* __restrict__ boc,
    float* __restrict__ esq, float* __restrict__ esct,
    float* __restrict__ oq, float* __restrict__ wb,
    unsigned int* __restrict__ flag,
    float* __restrict__ out, float* __restrict__ attn_out)
{
    __shared__ __align__(16) float smem[64*INPAD + 64*PAD + 64*TPAD];
    int t = threadIdx.x;

    // ======================= phase 1: projections ==========================
    if (blockIdx.x < 512) {
        float* in_t = smem;                        // [k][32]
        float* w_t  = smem + 64*INPAD;             // [k][64]
        float* tr   = smem + 64*INPAD + 64*PAD;    // [e][32], tp==1 only

        int tp = blockIdx.x >> 7;
        int rb = blockIdx.x & 127;
        // batch-aligned remap: bb = (rb&7)+8*(rb>>6), j = (rb>>3)&7
        int bb_x = (rb & 7) + ((rb >> 6) << 3);
        int jj   = (rb >> 3) & 7;
        int r0 = bb_x * 256 + jj * 32;

        const float* src = (tp & 1) ? bank : query;      // tp 1,3 -> bank
        const float* W   = (tp == 0) ? Wq : (tp == 1) ? Wc : (tp == 2) ? Woq : Woc;

        #pragma unroll
        for (int it = 0; it < 2; ++it) {
            int g = it * 256 + t;
            int kc4 = g & 15, row = g >> 4;              // row 0..31
            float4 v = *reinterpret_cast<const float4*>(src + (r0 + row) * D + kc4 * 4);
            in_t[(kc4*4+0)*INPAD + row] = v.x; in_t[(kc4*4+1)*INPAD + row] = v.y;
            in_t[(kc4*4+2)*INPAD + row] = v.z; in_t[(kc4*4+3)*INPAD + row] = v.w;
        }
        #pragma unroll
        for (int it = 0; it < 4; ++it) {
            int g = it * 256 + t;
            int kc = (g >> 8) * 4 + (g & 3);
            int row = (g >> 2) & 63;
            float4 w = *reinterpret_cast<const float4*>(W + row * D + kc * 4);
            w_t[(kc*4+0)*PAD + row] = w.x; w_t[(kc*4+1)*PAD + row] = w.y;
            w_t[(kc*4+2)*PAD + row] = w.z; w_t[(kc*4+3)*PAD + row] = w.w;
        }
        __syncthreads();

        int cg_ = t & 15, rg = t >> 4;
        float acc[2][4];
        #pragma unroll
        for (int i = 0; i < 2; ++i)
            #pragma unroll
            for (int j = 0; j < 4; ++j) acc[i][j] = 0.f;

        #pragma unroll 8
        for (int k = 0; k < 64; ++k) {
            float2 a2 = *reinterpret_cast<const float2*>(&in_t[k * INPAD + rg * 2]);
            float4 w4 = *reinterpret_cast<const float4*>(&w_t [k * PAD + cg_ * 4]);
            acc[0][0]=fmaf(a2.x,w4.x,acc[0][0]); acc[0][1]=fmaf(a2.x,w4.y,acc[0][1]);
            acc[0][2]=fmaf(a2.x,w4.z,acc[0][2]); acc[0][3]=fmaf(a2.x,w4.w,acc[0][3]);
            acc[1][0]=fmaf(a2.y,w4.x,acc[1][0]); acc[1][1]=fmaf(a2.y,w4.y,acc[1][1]);
            acc[1][2]=fmaf(a2.y,w4.z,acc[1][2]); acc[1][3]=fmaf(a2.y,w4.w,acc[1][3]);
        }

        float4 b4 = {0.f, 0.f, 0.f, 0.f};
        if (tp == 1) b4 = *reinterpret_cast<const float4*>(bc  + cg_ * 4);
        if (tp == 3) b4 = *reinterpret_cast<const float4*>(boc + cg_ * 4);

        if (tp == 1) {
            #pragma unroll
            for (int i = 0; i < 2; ++i) {
                tr[(cg_*4+0)*TPAD + rg*2+i] = exp2f(TS * (acc[i][0] + b4.x));
                tr[(cg_*4+1)*TPAD + rg*2+i] = exp2f(TS * (acc[i][1] + b4.y));
                tr[(cg_*4+2)*TPAD + rg*2+i] = exp2f(TS * (acc[i][2] + b4.z));
                tr[(cg_*4+3)*TPAD + rg*2+i] = exp2f(TS * (acc[i][3] + b4.w));
            }
            __syncthreads();
            int bb = r0 >> 8;            // batch index
            int cbase = r0 & 255;        // c offset within batch
            #pragma unroll
            for (int it = 0; it < 2; ++it) {
                int g = it * 256 + t;
                int d4 = g >> 5, cl = g & 31;
                float4 o;
                o.x = tr[(4*d4+0)*TPAD + cl];
                o.y = tr[(4*d4+1)*TPAD + cl];
                o.z = tr[(4*d4+2)*TPAD + cl];
                o.w = tr[(4*d4+3)*TPAD + cl];
                *reinterpret_cast<float4*>(esct + ((bb*16 + d4)*CP4 + cbase + cl)*4) = o;
            }
        } else {
            float* dst = (tp == 0) ? esq : (tp == 2) ? oq : wb;
            #pragma unroll
            for (int i = 0; i < 2; ++i) {
                float4 o;
                o.x = acc[i][0] + b4.x; o.y = acc[i][1] + b4.y;
                o.z = acc[i][2] + b4.z; o.w = acc[i][3] + b4.w;
                if (tp == 0) {
                    o.x = exp2f(TS * o.x); o.y = exp2f(TS * o.y);
                    o.z = exp2f(TS * o.z); o.w = exp2f(TS * o.w);
                }
                *reinterpret_cast<float4*>(dst + (r0 + rg*2 + i) * D + cg_ * 4) = o;
            }
        }
    }

    // block-wide: all phase-1 global stores drained (per-wave vmcnt before
    // barrier) and all phase-1 LDS reads complete (overlay safety).
    __syncthreads();

    // producer signal: agent-scope RELEASE (one L2 writeback per producer)
    if (blockIdx.x < 512 && t == 0)
        __hip_atomic_fetch_add(flag, 1u, __ATOMIC_RELEASE, __HIP_MEMORY_SCOPE_AGENT);

    // ---- attn decode + mask prefetch (input-only, overlaps the spin) ----
    int c = t;
    int p = blockIdx.x;
    int b = (p & 7) + ((p >> 9) << 3);
    int qb = (p >> 3) & 63;
    int bq0 = b * LQ + qb * QT;
    int lane = t & 63, wv = t >> 6;

    unsigned char mb[QT];
    #pragma unroll
    for (int qi = 0; qi < QT; ++qi) mb[qi] = mask[(bq0 + qi) * LC + c];

    // ---- spin RELAXED (no per-poll cache maintenance), then ONE acquire ----
    if (t == 0) {
        while (__hip_atomic_load(flag, __ATOMIC_RELAXED, __HIP_MEMORY_SCOPE_AGENT) < 512u)
            __builtin_amdgcn_s_sleep(8);
        // one-time publish: acquire load invalidates stale cached lines
        (void)__hip_atomic_load(flag, __ATOMIC_ACQUIRE, __HIP_MEMORY_SCOPE_AGENT);
    }
    __syncthreads();

    // ======================= phase 2: attention ============================
    float* esq_lds = smem;                                       // [QT][D]
    float (*a_lds)[LC] = reinterpret_cast<float(*)[LC]>(smem + QT*D);
    float* part_lds = smem + QT*D + QT*LC;                       // [4*QT*64]
    float* red_s    = smem + QT*D + QT*LC + 4*QT*64;             // [4*QT]

    // stage esq: one coalesced 1KB read (4 rows x 64 = 1 float/thread)
    esq_lds[t] = esq[bq0 * D + t];
    __syncthreads();

    const float4* ep4 = reinterpret_cast<const float4*>(esct) + b*16*CP4 + c;

    float s[QT];
    #pragma unroll
    for (int qi = 0; qi < QT; ++qi) s[qi] = 0.f;

    // score: esq via wave-uniform ds_read_b128 broadcast, Ws via s_load,
    // 4-way-paired rcp body
    #pragma unroll
    for (int kb = 0; kb < 4; ++kb) {
        float4 ec4[4];
        #pragma unroll
        for (int j = 0; j < 4; ++j) ec4[j] = ep4[(kb*4 + j) * CP4];
        #pragma unroll
        for (int j = 0; j < 4; ++j) {
            const int d0 = kb * 16 + j * 4;
            float w0 = Ws[d0+0], w1 = Ws[d0+1];
            float w2 = Ws[d0+2], w3 = Ws[d0+3];
            #pragma unroll
            for (int qi = 0; qi < QT; ++qi) {
                float4 e4 = *reinterpret_cast<const float4*>(&esq_lds[qi*D + d0]);
                float ax = fmaf(ec4[j].x, e4.x, 1.0f);
                float ay = fmaf(ec4[j].y, e4.y, 1.0f);
                float az = fmaf(ec4[j].z, e4.z, 1.0f);
                float aw = fmaf(ec4[j].w, e4.w, 1.0f);
                float pxy = ax * ay, pzw = az * aw;
                float nxy = fmaf(w0, ay, w1 * ax);
                float nzw = fmaf(w2, aw, w3 * az);
                float N   = fmaf(nxy, pzw, nzw * pxy);
                s[qi] = fmaf(N, __builtin_amdgcn_rcpf(pxy * pzw), s[qi]);
            }
        }
    }

    // unnormalized weights: tanh-bounded scores -> no max-subtraction needed
    float a[QT];
    #pragma unroll
    for (int qi = 0; qi < QT; ++qi) {
        a[qi] = mb[qi] ? 0.0f : exp2f(-TS * s[qi]);
    }

    // stage UNNORMALIZED weights for context; SUM reduce shares the barrier
    #pragma unroll
    for (int qi = 0; qi < QT; ++qi) a_lds[qi][c] = a[qi];
    #pragma unroll
    for (int qi = 0; qi < QT; ++qi) {
        float ss = a[qi];
        #pragma unroll
        for (int o = 32; o > 0; o >>= 1) ss += __shfl_xor(ss, o);
        if (lane == 0) red_s[wv * QT + qi] = ss;
    }
    __syncthreads();

    float rs[QT];
    #pragma unroll
    for (int qi = 0; qi < QT; ++qi) {
        float SUM = (red_s[qi] + red_s[QT + qi]) + (red_s[2*QT + qi] + red_s[3*QT + qi]);
        rs[qi] = __builtin_amdgcn_rcpf(SUM);
    }

    // normalized attention output (terminal stores, off critical path)
    #pragma unroll
    for (int qi = 0; qi < QT; ++qi)
        attn_out[(bq0 + qi) * LC + c] = a[qi] * rs[qi];

    // fused context+output-proj on UNNORMALIZED weights; wave g owns
    // c=g*64..+63; a_lds read as wave-uniform ds_read_b128 broadcasts
    {
        int g = wv;
        float acc[QT];
        #pragma unroll
        for (int qi = 0; qi < QT; ++qi) acc[qi] = 0.f;
        const float* wbp = wb + (b * LC + g * 64) * D + lane;
        #pragma unroll
        for (int i0 = 0; i0 < 64; i0 += 4) {
            float4 A0 = *reinterpret_cast<const float4*>(&a_lds[0][g*64 + i0]);
            float4 A1 = *reinterpret_cast<const float4*>(&a_lds[1][g*64 + i0]);
            float4 A2 = *reinterpret_cast<const float4*>(&a_lds[2][g*64 + i0]);
            float4 A3 = *reinterpret_cast<const float4*>(&a_lds[3][g*64 + i0]);
            float w0 = wbp[(i0+0) * D];
            float w1 = wbp[(i0+1) * D];
            float w2 = wbp[(i0+2) * D];
            float w3 = wbp[(i0+3) * D];
            acc[0] = fmaf(A0.x, w0, acc[0]); acc[1] = fmaf(A1.x, w0, acc[1]);
            acc[2] = fmaf(A2.x, w0, acc[2]); acc[3] = fmaf(A3.x, w0, acc[3]);
            acc[0] = fmaf(A0.y, w1, acc[0]); acc[1] = fmaf(A1.y, w1, acc[1]);
            acc[2] = fmaf(A2.y, w1, acc[2]); acc[3] = fmaf(A3.y, w1, acc[3]);
            acc[0] = fmaf(A0.z, w2, acc[0]); acc[1] = fmaf(A1.z, w2, acc[1]);
            acc[2] = fmaf(A2.z, w2, acc[2]); acc[3] = fmaf(A3.z, w2, acc[3]);
            acc[0] = fmaf(A0.w, w3, acc[0]); acc[1] = fmaf(A1.w, w3, acc[1]);
            acc[2] = fmaf(A2.w, w3, acc[2]); acc[3] = fmaf(A3.w, w3, acc[3]);
        }
        #pragma unroll
        for (int qi = 0; qi < QT; ++qi)
            part_lds[(g * QT + qi) * 64 + lane] = acc[qi];
    }
    __syncthreads();

    {
        int qi = t >> 6, e = t & 63;
        float ps = (part_lds[(0 * QT + qi) * 64 + e] + part_lds[(1 * QT + qi) * 64 + e])
                 + (part_lds[(2 * QT + qi) * 64 + e] + part_lds[(3 * QT + qi) * 64 + e]);
        out[bq0 * D + t] = fmaf(ps, rs[qi], oq[bq0 * D + t]);
    }
}

extern "C" void kernel_launch(void* const* d_in, const int* in_sizes, int n_in,
                              void* d_out, int out_size, void* d_ws, size_t ws_size,
                              hipStream_t stream) {
    const float* query = (const float*)d_in[0];
    const float* bank  = (const float*)d_in[1];
    const unsigned char* mask = (const unsigned char*)d_in[2];
    const float* Wq  = (const float*)d_in[3];
    const float* Wc  = (const float*)d_in[4];
    const float* bc  = (const float*)d_in[5];
    const float* Ws  = (const float*)d_in[6];
    // d_in[7] = bs: row-constant, cancels in softmax
    const float* Woq = (const float*)d_in[8];
    const float* Woc = (const float*)d_in[9];
    const float* boc = (const float*)d_in[10];

    float* out  = (float*)d_out;             // [B,LQ,D]
    float* attn = out + B * LQ * D;          // [B,LQ,LC]

    float* esq  = (float*)d_ws;              // [B*LQ, D]
    float* esct = esq + B * LQ * D;          // [B][16 d4][CP4] float4-interleaved
    float* oq   = esct + B * 16 * CP4 * 4;   // [B*LQ, D]
    float* wb   = oq + B * LQ * D;           // [B*LC, D]
    unsigned int* flag = (unsigned int*)(wb + B * LC * D);

    hipMemsetAsync(flag, 0, sizeof(unsigned int), stream);
    fused_kernel<<<B * LQ / QT, 256, 0, stream>>>(
        query, bank, mask, Wq, Wc, bc, Ws, Woq, Woc, boc,
        esq, esct, oq, wb, flag, out, attn);
}

// Round 10
// 47.174 us; speedup vs baseline: 2.0436x; 1.7135x over previous
//
#include <hip/hip_runtime.h>
#include <math.h>

#define B  16
#define LQ 256
#define LC 256
#define D  64
#define QT 4
#define TS   2.88539008177793f    // 2*log2(e)
#define L2E  1.44269504088896f    // log2(e)
#define PAD  72                   // LDS row stride (floats) for w_t [k][64]
#define INPAD 36                  // LDS row stride for in_t [k][32]
#define TPAD 33                   // LDS row stride for transpose tile [e][32]
#define CP4  264                  // esct pitch in float4 units (4224B, non-pow2)
#define FSTRIDE 32                // flag padding: one uint per 128B line

// ---------------------------------------------------------------------------
// fused_kernel: ONE plain launch, 1024 blocks x 256 threads, 4 blocks/CU
// co-resident. R8/R9 proved fusion correctness; counters showed ~10.5us of
// real work (VALUBusy*dur) inside 96/78us walls -> barrier mechanics dominate.
// R9->R10 refined theory: ALL barrier traffic (512 release atomicAdds + every
// poll from 1024 blocks) hit ONE 128B line; agent-scope ops serialize at the
// line's LLC slice (~50-100cyc each) -> tens of us of queueing.
// R10 fix: SHARD the barrier into 16 PER-BATCH flags on separate cache lines.
// Batch bb has exactly 32 producers (8 row-chunks x 4 proj types); consumers
// of batch b poll only flag[b] (relaxed, s_sleep backoff) until 32, then one
// acquire load publishes. Bonus: per-batch rendezvous pipelines -- batch b's
// consumers start as soon as THEIR producers finish, not the whole grid.
// ---------------------------------------------------------------------------
__global__ __launch_bounds__(256, 4) void fused_kernel(
    const float* __restrict__ query, const float* __restrict__ bank,
    const unsigned char* __restrict__ mask,
    const float* __restrict__ Wq, const float* __restrict__ Wc,
    const float* __restrict__ bc, const float* __restrict__ Ws,
    const float* __restrict__ Woq, const float* __restrict__ Woc,
    const float* __restrict__ boc,
    float* __restrict__ esq, float* __restrict__ esct,
    float* __restrict__ oq, float* __restrict__ wb,
    unsigned int* __restrict__ flags,
    float* __restrict__ out, float* __restrict__ attn_out)
{
    __shared__ __align__(16) float smem[64*INPAD + 64*PAD + 64*TPAD];
    int t = threadIdx.x;

    // producer's batch (valid for blockIdx.x < 512): bb = (rb&7)+8*(rb>>6)
    int rb_ = blockIdx.x & 127;
    int prod_bb = (rb_ & 7) + ((rb_ >> 6) << 3);

    // ======================= phase 1: projections ==========================
    if (blockIdx.x < 512) {
        float* in_t = smem;                        // [k][32]
        float* w_t  = smem + 64*INPAD;             // [k][64]
        float* tr   = smem + 64*INPAD + 64*PAD;    // [e][32], tp==1 only

        int tp = blockIdx.x >> 7;
        int jj = (rb_ >> 3) & 7;
        int r0 = prod_bb * 256 + jj * 32;

        const float* src = (tp & 1) ? bank : query;      // tp 1,3 -> bank
        const float* W   = (tp == 0) ? Wq : (tp == 1) ? Wc : (tp == 2) ? Woq : Woc;

        #pragma unroll
        for (int it = 0; it < 2; ++it) {
            int g = it * 256 + t;
            int kc4 = g & 15, row = g >> 4;              // row 0..31
            float4 v = *reinterpret_cast<const float4*>(src + (r0 + row) * D + kc4 * 4);
            in_t[(kc4*4+0)*INPAD + row] = v.x; in_t[(kc4*4+1)*INPAD + row] = v.y;
            in_t[(kc4*4+2)*INPAD + row] = v.z; in_t[(kc4*4+3)*INPAD + row] = v.w;
        }
        #pragma unroll
        for (int it = 0; it < 4; ++it) {
            int g = it * 256 + t;
            int kc = (g >> 8) * 4 + (g & 3);
            int row = (g >> 2) & 63;
            float4 w = *reinterpret_cast<const float4*>(W + row * D + kc * 4);
            w_t[(kc*4+0)*PAD + row] = w.x; w_t[(kc*4+1)*PAD + row] = w.y;
            w_t[(kc*4+2)*PAD + row] = w.z; w_t[(kc*4+3)*PAD + row] = w.w;
        }
        __syncthreads();

        int cg_ = t & 15, rg = t >> 4;
        float acc[2][4];
        #pragma unroll
        for (int i = 0; i < 2; ++i)
            #pragma unroll
            for (int j = 0; j < 4; ++j) acc[i][j] = 0.f;

        #pragma unroll 8
        for (int k = 0; k < 64; ++k) {
            float2 a2 = *reinterpret_cast<const float2*>(&in_t[k * INPAD + rg * 2]);
            float4 w4 = *reinterpret_cast<const float4*>(&w_t [k * PAD + cg_ * 4]);
            acc[0][0]=fmaf(a2.x,w4.x,acc[0][0]); acc[0][1]=fmaf(a2.x,w4.y,acc[0][1]);
            acc[0][2]=fmaf(a2.x,w4.z,acc[0][2]); acc[0][3]=fmaf(a2.x,w4.w,acc[0][3]);
            acc[1][0]=fmaf(a2.y,w4.x,acc[1][0]); acc[1][1]=fmaf(a2.y,w4.y,acc[1][1]);
            acc[1][2]=fmaf(a2.y,w4.z,acc[1][2]); acc[1][3]=fmaf(a2.y,w4.w,acc[1][3]);
        }

        float4 b4 = {0.f, 0.f, 0.f, 0.f};
        if (tp == 1) b4 = *reinterpret_cast<const float4*>(bc  + cg_ * 4);
        if (tp == 3) b4 = *reinterpret_cast<const float4*>(boc + cg_ * 4);

        if (tp == 1) {
            #pragma unroll
            for (int i = 0; i < 2; ++i) {
                tr[(cg_*4+0)*TPAD + rg*2+i] = exp2f(TS * (acc[i][0] + b4.x));
                tr[(cg_*4+1)*TPAD + rg*2+i] = exp2f(TS * (acc[i][1] + b4.y));
                tr[(cg_*4+2)*TPAD + rg*2+i] = exp2f(TS * (acc[i][2] + b4.z));
                tr[(cg_*4+3)*TPAD + rg*2+i] = exp2f(TS * (acc[i][3] + b4.w));
            }
            __syncthreads();
            int bb = r0 >> 8;            // batch index
            int cbase = r0 & 255;        // c offset within batch
            #pragma unroll
            for (int it = 0; it < 2; ++it) {
                int g = it * 256 + t;
                int d4 = g >> 5, cl = g & 31;
                float4 o;
                o.x = tr[(4*d4+0)*TPAD + cl];
                o.y = tr[(4*d4+1)*TPAD + cl];
                o.z = tr[(4*d4+2)*TPAD + cl];
                o.w = tr[(4*d4+3)*TPAD + cl];
                *reinterpret_cast<float4*>(esct + ((bb*16 + d4)*CP4 + cbase + cl)*4) = o;
            }
        } else {
            float* dst = (tp == 0) ? esq : (tp == 2) ? oq : wb;
            #pragma unroll
            for (int i = 0; i < 2; ++i) {
                float4 o;
                o.x = acc[i][0] + b4.x; o.y = acc[i][1] + b4.y;
                o.z = acc[i][2] + b4.z; o.w = acc[i][3] + b4.w;
                if (tp == 0) {
                    o.x = exp2f(TS * o.x); o.y = exp2f(TS * o.y);
                    o.z = exp2f(TS * o.z); o.w = exp2f(TS * o.w);
                }
                *reinterpret_cast<float4*>(dst + (r0 + rg*2 + i) * D + cg_ * 4) = o;
            }
        }
    }

    // block-wide: all phase-1 global stores drained (per-wave vmcnt before
    // barrier) and all phase-1 LDS reads complete (overlay safety).
    __syncthreads();

    // producer signal: agent-scope RELEASE add on THIS BATCH's flag line
    if (blockIdx.x < 512 && t == 0)
        __hip_atomic_fetch_add(&flags[prod_bb * FSTRIDE], 1u,
                               __ATOMIC_RELEASE, __HIP_MEMORY_SCOPE_AGENT);

    // ---- attn decode + mask prefetch (input-only, overlaps the wait) ----
    int c = t;
    int p = blockIdx.x;
    int b = (p & 7) + ((p >> 9) << 3);
    int qb = (p >> 3) & 63;
    int bq0 = b * LQ + qb * QT;
    int lane = t & 63, wv = t >> 6;

    unsigned char mb[QT];
    #pragma unroll
    for (int qi = 0; qi < QT; ++qi) mb[qi] = mask[(bq0 + qi) * LC + c];

    // ---- wait for THIS batch's 32 producers: relaxed poll + one acquire ----
    if (t == 0) {
        while (__hip_atomic_load(&flags[b * FSTRIDE], __ATOMIC_RELAXED,
                                 __HIP_MEMORY_SCOPE_AGENT) < 32u)
            __builtin_amdgcn_s_sleep(32);
        (void)__hip_atomic_load(&flags[b * FSTRIDE], __ATOMIC_ACQUIRE,
                                __HIP_MEMORY_SCOPE_AGENT);
    }
    __syncthreads();

    // ======================= phase 2: attention ============================
    float* esq_lds = smem;                                       // [QT][D]
    float (*a_lds)[LC] = reinterpret_cast<float(*)[LC]>(smem + QT*D);
    float* part_lds = smem + QT*D + QT*LC;                       // [4*QT*64]
    float* red_s    = smem + QT*D + QT*LC + 4*QT*64;             // [4*QT]

    // stage esq: one coalesced 1KB read (4 rows x 64 = 1 float/thread)
    esq_lds[t] = esq[bq0 * D + t];
    __syncthreads();

    const float4* ep4 = reinterpret_cast<const float4*>(esct) + b*16*CP4 + c;

    float s[QT];
    #pragma unroll
    for (int qi = 0; qi < QT; ++qi) s[qi] = 0.f;

    // score: esq via wave-uniform ds_read_b128 broadcast, Ws via s_load,
    // 4-way-paired rcp body
    #pragma unroll
    for (int kb = 0; kb < 4; ++kb) {
        float4 ec4[4];
        #pragma unroll
        for (int j = 0; j < 4; ++j) ec4[j] = ep4[(kb*4 + j) * CP4];
        #pragma unroll
        for (int j = 0; j < 4; ++j) {
            const int d0 = kb * 16 + j * 4;
            float w0 = Ws[d0+0], w1 = Ws[d0+1];
            float w2 = Ws[d0+2], w3 = Ws[d0+3];
            #pragma unroll
            for (int qi = 0; qi < QT; ++qi) {
                float4 e4 = *reinterpret_cast<const float4*>(&esq_lds[qi*D + d0]);
                float ax = fmaf(ec4[j].x, e4.x, 1.0f);
                float ay = fmaf(ec4[j].y, e4.y, 1.0f);
                float az = fmaf(ec4[j].z, e4.z, 1.0f);
                float aw = fmaf(ec4[j].w, e4.w, 1.0f);
                float pxy = ax * ay, pzw = az * aw;
                float nxy = fmaf(w0, ay, w1 * ax);
                float nzw = fmaf(w2, aw, w3 * az);
                float N   = fmaf(nxy, pzw, nzw * pxy);
                s[qi] = fmaf(N, __builtin_amdgcn_rcpf(pxy * pzw), s[qi]);
            }
        }
    }

    // unnormalized weights: tanh-bounded scores -> no max-subtraction needed
    float a[QT];
    #pragma unroll
    for (int qi = 0; qi < QT; ++qi) {
        a[qi] = mb[qi] ? 0.0f : exp2f(-TS * s[qi]);
    }

    // stage UNNORMALIZED weights for context; SUM reduce shares the barrier
    #pragma unroll
    for (int qi = 0; qi < QT; ++qi) a_lds[qi][c] = a[qi];
    #pragma unroll
    for (int qi = 0; qi < QT; ++qi) {
        float ss = a[qi];
        #pragma unroll
        for (int o = 32; o > 0; o >>= 1) ss += __shfl_xor(ss, o);
        if (lane == 0) red_s[wv * QT + qi] = ss;
    }
    __syncthreads();

    float rs[QT];
    #pragma unroll
    for (int qi = 0; qi < QT; ++qi) {
        float SUM = (red_s[qi] + red_s[QT + qi]) + (red_s[2*QT + qi] + red_s[3*QT + qi]);
        rs[qi] = __builtin_amdgcn_rcpf(SUM);
    }

    // normalized attention output (terminal stores, off critical path)
    #pragma unroll
    for (int qi = 0; qi < QT; ++qi)
        attn_out[(bq0 + qi) * LC + c] = a[qi] * rs[qi];

    // fused context+output-proj on UNNORMALIZED weights; wave g owns
    // c=g*64..+63; a_lds read as wave-uniform ds_read_b128 broadcasts
    {
        int g = wv;
        float acc[QT];
        #pragma unroll
        for (int qi = 0; qi < QT; ++qi) acc[qi] = 0.f;
        const float* wbp = wb + (b * LC + g * 64) * D + lane;
        #pragma unroll
        for (int i0 = 0; i0 < 64; i0 += 4) {
            float4 A0 = *reinterpret_cast<const float4*>(&a_lds[0][g*64 + i0]);
            float4 A1 = *reinterpret_cast<const float4*>(&a_lds[1][g*64 + i0]);
            float4 A2 = *reinterpret_cast<const float4*>(&a_lds[2][g*64 + i0]);
            float4 A3 = *reinterpret_cast<const float4*>(&a_lds[3][g*64 + i0]);
            float w0 = wbp[(i0+0) * D];
            float w1 = wbp[(i0+1) * D];
            float w2 = wbp[(i0+2) * D];
            float w3 = wbp[(i0+3) * D];
            acc[0] = fmaf(A0.x, w0, acc[0]); acc[1] = fmaf(A1.x, w0, acc[1]);
            acc[2] = fmaf(A2.x, w0, acc[2]); acc[3] = fmaf(A3.x, w0, acc[3]);
            acc[0] = fmaf(A0.y, w1, acc[0]); acc[1] = fmaf(A1.y, w1, acc[1]);
            acc[2] = fmaf(A2.y, w1, acc[2]); acc[3] = fmaf(A3.y, w1, acc[3]);
            acc[0] = fmaf(A0.z, w2, acc[0]); acc[1] = fmaf(A1.z, w2, acc[1]);
            acc[2] = fmaf(A2.z, w2, acc[2]); acc[3] = fmaf(A3.z, w2, acc[3]);
            acc[0] = fmaf(A0.w, w3, acc[0]); acc[1] = fmaf(A1.w, w3, acc[1]);
            acc[2] = fmaf(A2.w, w3, acc[2]); acc[3] = fmaf(A3.w, w3, acc[3]);
        }
        #pragma unroll
        for (int qi = 0; qi < QT; ++qi)
            part_lds[(g * QT + qi) * 64 + lane] = acc[qi];
    }
    __syncthreads();

    {
        int qi = t >> 6, e = t & 63;
        float ps = (part_lds[(0 * QT + qi) * 64 + e] + part_lds[(1 * QT + qi) * 64 + e])
                 + (part_lds[(2 * QT + qi) * 64 + e] + part_lds[(3 * QT + qi) * 64 + e]);
        out[bq0 * D + t] = fmaf(ps, rs[qi], oq[bq0 * D + t]);
    }
}

extern "C" void kernel_launch(void* const* d_in, const int* in_sizes, int n_in,
                              void* d_out, int out_size, void* d_ws, size_t ws_size,
                              hipStream_t stream) {
    const float* query = (const float*)d_in[0];
    const float* bank  = (const float*)d_in[1];
    const unsigned char* mask = (const unsigned char*)d_in[2];
    const float* Wq  = (const float*)d_in[3];
    const float* Wc  = (const float*)d_in[4];
    const float* bc  = (const float*)d_in[5];
    const float* Ws  = (const float*)d_in[6];
    // d_in[7] = bs: row-constant, cancels in softmax
    const float* Woq = (const float*)d_in[8];
    const float* Woc = (const float*)d_in[9];
    const float* boc = (const float*)d_in[10];

    float* out  = (float*)d_out;             // [B,LQ,D]
    float* attn = out + B * LQ * D;          // [B,LQ,LC]

    float* esq  = (float*)d_ws;              // [B*LQ, D]
    float* esct = esq + B * LQ * D;          // [B][16 d4][CP4] float4-interleaved
    float* oq   = esct + B * 16 * CP4 * 4;   // [B*LQ, D]
    float* wb   = oq + B * LQ * D;           // [B*LC, D]
    unsigned int* flags = (unsigned int*)(wb + B * LC * D);  // 16 x 128B lines

    hipMemsetAsync(flags, 0, B * FSTRIDE * sizeof(unsigned int), stream);
    fused_kernel<<<B * LQ / QT, 256, 0, stream>>>(
        query, bank, mask, Wq, Wc, bc, Ws, Woq, Woc, boc,
        esq, esct, oq, wb, flags, out, attn);
}

// Round 11
// 24.141 us; speedup vs baseline: 3.9935x; 1.9541x over previous
//
#include <hip/hip_runtime.h>
#include <math.h>

#define B  16
#define LQ 256
#define LC 256
#define D  64
#define QT 8
#define TS   2.88539008177793f    // 2*log2(e)
#define L2E  1.44269504088896f    // log2(e)
#define PAD  72                   // LDS row stride (floats) for w_t [k][64]
#define INPAD 36                  // LDS row stride for in_t [k][32]
#define TPAD 33                   // LDS row stride for transpose tile [e][32]
#define CP4  264                  // esct pitch in float4 units (4224B, non-pow2)

// ---------------------------------------------------------------------------
// proj_kernel: 32x64x64 GEMM per block (512 blocks = 4 types x 128 row-blocks)
//  R2/R4/R6-proven LDS version, verbatim. (Fused-kernel arc R7-R10 abandoned
//  per pre-commit: in-kernel cross-block barriers cost 30-85us on this chip --
//  acquire-side XCD-L2 invalidate traffic; two-dispatch overhead ~12us wins.)
//  XCD-ALIGNED row-chunk remap: chunk for batch bb lands on block id%8==bb%8,
//  matching attn_kernel's batch->XCD pin.
// ---------------------------------------------------------------------------
__global__ __launch_bounds__(256) void proj_kernel(
    const float* __restrict__ query, const float* __restrict__ bank,
    const float* __restrict__ Wq, const float* __restrict__ Wc,
    const float* __restrict__ bc,
    const float* __restrict__ Woq, const float* __restrict__ Woc,
    const float* __restrict__ boc,
    float* __restrict__ esq, float* __restrict__ esct,
    float* __restrict__ oq, float* __restrict__ wb)
{
    int t  = threadIdx.x;
    int tp = blockIdx.x >> 7;
    int rb = blockIdx.x & 127;
    // batch-aligned remap: bb = (rb&7)+8*(rb>>6) in [0,16), j = (rb>>3)&7
    int bb_x = (rb & 7) + ((rb >> 6) << 3);
    int jj   = (rb >> 3) & 7;
    int r0 = bb_x * 256 + jj * 32;

    __shared__ __align__(16) float in_t[64 * INPAD]; // [k][32]
    __shared__ __align__(16) float w_t [64 * PAD];   // [k][64]
    __shared__ float tr[64 * TPAD];                  // [e][32], tp==1 only

    const float* src = (tp & 1) ? bank : query;      // tp 1,3 -> bank
    const float* W   = (tp == 0) ? Wq : (tp == 1) ? Wc : (tp == 2) ? Woq : Woc;

    #pragma unroll
    for (int it = 0; it < 2; ++it) {
        int g = it * 256 + t;
        int kc4 = g & 15, row = g >> 4;              // row 0..31
        float4 v = *reinterpret_cast<const float4*>(src + (r0 + row) * D + kc4 * 4);
        in_t[(kc4*4+0)*INPAD + row] = v.x; in_t[(kc4*4+1)*INPAD + row] = v.y;
        in_t[(kc4*4+2)*INPAD + row] = v.z; in_t[(kc4*4+3)*INPAD + row] = v.w;
    }
    #pragma unroll
    for (int it = 0; it < 4; ++it) {
        int g = it * 256 + t;
        int kc = (g >> 8) * 4 + (g & 3);
        int row = (g >> 2) & 63;
        float4 w = *reinterpret_cast<const float4*>(W + row * D + kc * 4);
        w_t[(kc*4+0)*PAD + row] = w.x; w_t[(kc*4+1)*PAD + row] = w.y;
        w_t[(kc*4+2)*PAD + row] = w.z; w_t[(kc*4+3)*PAD + row] = w.w;
    }
    __syncthreads();

    int cg = t & 15, rg = t >> 4;
    float acc[2][4];
    #pragma unroll
    for (int i = 0; i < 2; ++i)
        #pragma unroll
        for (int j = 0; j < 4; ++j) acc[i][j] = 0.f;

    #pragma unroll 8
    for (int k = 0; k < 64; ++k) {
        float2 a2 = *reinterpret_cast<const float2*>(&in_t[k * INPAD + rg * 2]);
        float4 w4 = *reinterpret_cast<const float4*>(&w_t [k * PAD + cg * 4]);
        acc[0][0]=fmaf(a2.x,w4.x,acc[0][0]); acc[0][1]=fmaf(a2.x,w4.y,acc[0][1]);
        acc[0][2]=fmaf(a2.x,w4.z,acc[0][2]); acc[0][3]=fmaf(a2.x,w4.w,acc[0][3]);
        acc[1][0]=fmaf(a2.y,w4.x,acc[1][0]); acc[1][1]=fmaf(a2.y,w4.y,acc[1][1]);
        acc[1][2]=fmaf(a2.y,w4.z,acc[1][2]); acc[1][3]=fmaf(a2.y,w4.w,acc[1][3]);
    }

    float4 b4 = {0.f, 0.f, 0.f, 0.f};
    if (tp == 1) b4 = *reinterpret_cast<const float4*>(bc  + cg * 4);
    if (tp == 3) b4 = *reinterpret_cast<const float4*>(boc + cg * 4);

    if (tp == 1) {
        // tr[e][c_local]
        #pragma unroll
        for (int i = 0; i < 2; ++i) {
            tr[(cg*4+0)*TPAD + rg*2+i] = exp2f(TS * (acc[i][0] + b4.x));
            tr[(cg*4+1)*TPAD + rg*2+i] = exp2f(TS * (acc[i][1] + b4.y));
            tr[(cg*4+2)*TPAD + rg*2+i] = exp2f(TS * (acc[i][2] + b4.z));
            tr[(cg*4+3)*TPAD + rg*2+i] = exp2f(TS * (acc[i][3] + b4.w));
        }
        __syncthreads();
        int bb = r0 >> 8;            // batch index
        int cbase = r0 & 255;        // c offset within batch
        // 512 float4 outputs: [d4 0..15][cl 0..31], coalesced stores
        #pragma unroll
        for (int it = 0; it < 2; ++it) {
            int g = it * 256 + t;
            int d4 = g >> 5, cl = g & 31;
            float4 o;
            o.x = tr[(4*d4+0)*TPAD + cl];
            o.y = tr[(4*d4+1)*TPAD + cl];
            o.z = tr[(4*d4+2)*TPAD + cl];
            o.w = tr[(4*d4+3)*TPAD + cl];
            *reinterpret_cast<float4*>(esct + ((bb*16 + d4)*CP4 + cbase + cl)*4) = o;
        }
    } else {
        float* dst = (tp == 0) ? esq : (tp == 2) ? oq : wb;
        #pragma unroll
        for (int i = 0; i < 2; ++i) {
            float4 o;
            o.x = acc[i][0] + b4.x; o.y = acc[i][1] + b4.y;
            o.z = acc[i][2] + b4.z; o.w = acc[i][3] + b4.w;
            if (tp == 0) {
                o.x = exp2f(TS * o.x); o.y = exp2f(TS * o.y);
                o.z = exp2f(TS * o.z); o.w = exp2f(TS * o.w);
            }
            *reinterpret_cast<float4*>(dst + (r0 + rg*2 + i) * D + cg * 4) = o;
        }
    }
}

// ---------------------------------------------------------------------------
// attn_kernel: QT=8 (R11 change vs R6's QT=4): one block per (b, 8 q's),
//  512 blocks, 2/CU. Halves the per-batch panel re-read amplification
//  (esct+wb read by 32 blocks/batch instead of 64 -> L2 traffic 128->64MB)
//  and halves block tails; per-thread ILP doubles (8 independent acc chains)
//  to compensate 2 waves/SIMD. Score issue count unchanged by construction.
//  All R6-proven techniques kept: XCD batch pin (b%8==p%8), esq via LDS
//  broadcast, Ws via s_load, 4-way rcp pairing, deferred normalization,
//  max-free softmax. Epilogue recomputes rcp(SUM) from red_s (LDS) to avoid
//  runtime-indexing a register array (scratch-spill rule).
// ---------------------------------------------------------------------------
__global__ __launch_bounds__(256, 2) void attn_kernel(
    const unsigned char* __restrict__ mask,
    const float* __restrict__ esq_g, const float* __restrict__ esct_g,
    const float* __restrict__ Ws,
    const float* __restrict__ oq_g, const float* __restrict__ wb_g,
    float* __restrict__ out, float* __restrict__ attn_out)
{
    int t = threadIdx.x;
    int c = t;
    // ---- batch->XCD swizzle: bijective on [0,512), b%8 == p%8.
    int p = blockIdx.x;
    int b = (p & 7) + ((p >> 8) << 3);
    int qb = (p >> 3) & 31;
    int bq0 = b * LQ + qb * QT;
    int lane = t & 63, wv = t >> 6;

    __shared__ __align__(16) float esq_lds[QT * D];  // exp'd query scores, 2KB
    __shared__ __align__(16) float a_lds[QT][LC];    // UNNORM attn weights, 8KB
    __shared__ float part_lds[4 * QT * 64];          // 8KB
    __shared__ float red_s[4 * QT];

    // ---- stage esq: 512 floats, 2 coalesced reads/thread
    esq_lds[t]       = esq_g[bq0 * D + t];
    esq_lds[256 + t] = esq_g[bq0 * D + 256 + t];

    // prefetch mask bytes (coalesced)
    unsigned char mb[QT];
    #pragma unroll
    for (int qi = 0; qi < QT; ++qi) mb[qi] = mask[(bq0 + qi) * LC + c];

    __syncthreads();

    const float4* ep4 = reinterpret_cast<const float4*>(esct_g) + b*16*CP4 + c;

    float s[QT];
    #pragma unroll
    for (int qi = 0; qi < QT; ++qi) s[qi] = 0.f;

    // ---- score: 4 chunks of 16 d's; 4 float4 panel loads per chunk
    //      (amortized over 8 q's); esq via wave-uniform ds_read_b128
    //      broadcast, Ws via s_load; 4-way-paired rcp body ----
    #pragma unroll
    for (int kb = 0; kb < 4; ++kb) {
        float4 ec4[4];
        #pragma unroll
        for (int j = 0; j < 4; ++j) ec4[j] = ep4[(kb*4 + j) * CP4];
        #pragma unroll
        for (int j = 0; j < 4; ++j) {
            const int d0 = kb * 16 + j * 4;
            float w0 = Ws[d0+0], w1 = Ws[d0+1];
            float w2 = Ws[d0+2], w3 = Ws[d0+3];
            #pragma unroll
            for (int qi = 0; qi < QT; ++qi) {
                float4 e4 = *reinterpret_cast<const float4*>(&esq_lds[qi*D + d0]);
                float ax = fmaf(ec4[j].x, e4.x, 1.0f);
                float ay = fmaf(ec4[j].y, e4.y, 1.0f);
                float az = fmaf(ec4[j].z, e4.z, 1.0f);
                float aw = fmaf(ec4[j].w, e4.w, 1.0f);
                float pxy = ax * ay, pzw = az * aw;
                float nxy = fmaf(w0, ay, w1 * ax);
                float nzw = fmaf(w2, aw, w3 * az);
                float N   = fmaf(nxy, pzw, nzw * pxy);
                s[qi] = fmaf(N, __builtin_amdgcn_rcpf(pxy * pzw), s[qi]);
            }
        }
    }

    // unnormalized weights: tanh-bounded scores -> no max-subtraction needed
    float a[QT];
    #pragma unroll
    for (int qi = 0; qi < QT; ++qi) {
        a[qi] = mb[qi] ? 0.0f : exp2f(-TS * s[qi]);
    }

    // stage UNNORMALIZED weights for context; SUM reduce shares the barrier
    #pragma unroll
    for (int qi = 0; qi < QT; ++qi) a_lds[qi][c] = a[qi];
    #pragma unroll
    for (int qi = 0; qi < QT; ++qi) {
        float ss = a[qi];
        #pragma unroll
        for (int o = 32; o > 0; o >>= 1) ss += __shfl_xor(ss, o);
        if (lane == 0) red_s[wv * QT + qi] = ss;
    }
    __syncthreads();

    // normalized attention output (compile-time qi -> register rs ok here)
    #pragma unroll
    for (int qi = 0; qi < QT; ++qi) {
        float SUM = (red_s[qi] + red_s[QT + qi]) + (red_s[2*QT + qi] + red_s[3*QT + qi]);
        attn_out[(bq0 + qi) * LC + c] = a[qi] * __builtin_amdgcn_rcpf(SUM);
    }

    // ---- fused context+output-proj on UNNORMALIZED weights; wave g owns
    //      c=g*64..+63; a_lds read as wave-uniform ds_read_b128 broadcasts ----
    {
        int g = wv;
        float acc[QT];
        #pragma unroll
        for (int qi = 0; qi < QT; ++qi) acc[qi] = 0.f;
        const float* wbp = wb_g + (b * LC + g * 64) * D + lane;
        #pragma unroll
        for (int i0 = 0; i0 < 64; i0 += 4) {
            float4 A[QT];
            #pragma unroll
            for (int qi = 0; qi < QT; ++qi)
                A[qi] = *reinterpret_cast<const float4*>(&a_lds[qi][g*64 + i0]);
            float w0 = wbp[(i0+0) * D];
            float w1 = wbp[(i0+1) * D];
            float w2 = wbp[(i0+2) * D];
            float w3 = wbp[(i0+3) * D];
            #pragma unroll
            for (int qi = 0; qi < QT; ++qi) {
                acc[qi] = fmaf(A[qi].x, w0, acc[qi]);
                acc[qi] = fmaf(A[qi].y, w1, acc[qi]);
                acc[qi] = fmaf(A[qi].z, w2, acc[qi]);
                acc[qi] = fmaf(A[qi].w, w3, acc[qi]);
            }
        }
        #pragma unroll
        for (int qi = 0; qi < QT; ++qi)
            part_lds[(g * QT + qi) * 64 + lane] = acc[qi];
    }
    __syncthreads();

    // epilogue: 512 outputs, 2 per thread; runtime qi -> recompute rcp(SUM)
    // from red_s in LDS (no runtime-indexed register array)
    #pragma unroll
    for (int it = 0; it < 2; ++it) {
        int idx = it * 256 + t;
        int qi = idx >> 6, e = idx & 63;
        float SUM = (red_s[qi] + red_s[QT + qi]) + (red_s[2*QT + qi] + red_s[3*QT + qi]);
        float ps = (part_lds[(0 * QT + qi) * 64 + e] + part_lds[(1 * QT + qi) * 64 + e])
                 + (part_lds[(2 * QT + qi) * 64 + e] + part_lds[(3 * QT + qi) * 64 + e]);
        out[bq0 * D + idx] = fmaf(ps, __builtin_amdgcn_rcpf(SUM), oq_g[bq0 * D + idx]);
    }
}

extern "C" void kernel_launch(void* const* d_in, const int* in_sizes, int n_in,
                              void* d_out, int out_size, void* d_ws, size_t ws_size,
                              hipStream_t stream) {
    const float* query = (const float*)d_in[0];
    const float* bank  = (const float*)d_in[1];
    const unsigned char* mask = (const unsigned char*)d_in[2];
    const float* Wq  = (const float*)d_in[3];
    const float* Wc  = (const float*)d_in[4];
    const float* bc  = (const float*)d_in[5];
    const float* Ws  = (const float*)d_in[6];
    // d_in[7] = bs: row-constant, cancels in softmax
    const float* Woq = (const float*)d_in[8];
    const float* Woc = (const float*)d_in[9];
    const float* boc = (const float*)d_in[10];

    float* out  = (float*)d_out;             // [B,LQ,D]
    float* attn = out + B * LQ * D;          // [B,LQ,LC]

    float* esq  = (float*)d_ws;              // [B*LQ, D]
    float* esct = esq + B * LQ * D;          // [B][16 d4][CP4] float4-interleaved
    float* oq   = esct + B * 16 * CP4 * 4;   // [B*LQ, D]
    float* wb   = oq + B * LQ * D;           // [B*LC, D]

    proj_kernel<<<4 * 128, 256, 0, stream>>>(query, bank, Wq, Wc, bc,
                                             Woq, Woc, boc,
                                             esq, esct, oq, wb);
    attn_kernel<<<B * LQ / QT, 256, 0, stream>>>(mask, esq, esct, Ws,
                                                 oq, wb, out, attn);
}